// Round 6
// baseline (709.550 us; speedup 1.0000x reference)
//
#include <hip/hip_runtime.h>
#include <cstdint>
#include <cstddef>

typedef __bf16 bf16x8 __attribute__((ext_vector_type(8)));
typedef float f32x4 __attribute__((ext_vector_type(4)));
typedef unsigned short u16;
typedef unsigned int u32;
typedef unsigned short u16x8 __attribute__((ext_vector_type(8)));
typedef unsigned int u32x4v __attribute__((ext_vector_type(4)));

#define ROWS 32768       // B*T*S
#define DMODEL 1024
#define NQKV 1536        // H*HD + 2*KVH*HD
// folded softcap constants: logits z = dot*rq*rk*0.125, capped = 50*tanh(z/50)
//   e2 = exp2(dot*rq*rk * C1),  C1 = 2*0.125/50*log2(e)
//   p  = exp2(B2 - A2 * rcp(e2+1)),  A2 = 100*log2(e), B2 = 50*log2(e)
#define C1_ 0.0072134752044448170f
#define A2_ 144.26950408889634f
#define B2_ 72.13475204444817f

__device__ __forceinline__ u16 f2bf(float f) {
    unsigned u = __float_as_uint(f);
    u += 0x7fffu + ((u >> 16) & 1u);   // RNE
    return (u16)(u >> 16);
}
__device__ __forceinline__ float bf_lo(u32 u) { return __uint_as_float(u << 16); }
__device__ __forceinline__ float bf_hi(u32 u) { return __uint_as_float(u & 0xffff0000u); }
__device__ __forceinline__ u32 pack_rne(float lo, float hi) {
    return (u32)f2bf(lo) | ((u32)f2bf(hi) << 16);
}

// ---------------- elementwise f32 -> bf16 (x) ----------------
__global__ __launch_bounds__(256) void f32_to_bf16_vec(
    const float* __restrict__ in, u16* __restrict__ out, int n4)
{
    int i = blockIdx.x * 256 + threadIdx.x;
    if (i >= n4) return;
    float4 f = ((const float4*)in)[i];
    ushort4 u;
    u.x = f2bf(f.x); u.y = f2bf(f.y); u.z = f2bf(f.z); u.w = f2bf(f.w);
    ((ushort4*)out)[i] = u;
}

// ---------------- transpose f32 [R][C] -> bf16 [C][R] ----------------
__global__ __launch_bounds__(256) void transpose_bf16(
    const float* __restrict__ src, u16* __restrict__ dst, int R, int C)
{
    __shared__ float tile[32][33];
    int c0 = blockIdx.x * 32;
    int r0 = blockIdx.y * 32;
    int tx = threadIdx.x & 31;
    int ty = threadIdx.x >> 5;        // 0..7
#pragma unroll
    for (int i = 0; i < 32; i += 8)
        tile[ty + i][tx] = src[(size_t)(r0 + ty + i) * C + (c0 + tx)];
    __syncthreads();
#pragma unroll
    for (int i = 0; i < 32; i += 8)
        dst[(size_t)(c0 + ty + i) * R + (r0 + tx)] = f2bf(tile[tx][ty + i]);
}

// ---------------- MFMA GEMM: A[M][K] bf16 @ Bt[N][K] bf16 -> C[M][N] ----------------
// XCD-chunked swizzle, n-tile fastest inside a chunk. AHB: A is head-blocked
// [16][M][64] (attention output layout).
template<bool BF16OUT, int NY, bool AHB>
__global__ __launch_bounds__(256) void gemm_bt(
    const u16* __restrict__ A, const u16* __restrict__ Bt,
    void* __restrict__ Cout, int M, int N, int K)
{
    __shared__ u16 As[128][32];
    __shared__ u16 Bs[128][32];
    const int tid  = threadIdx.x;
    const int wave = tid >> 6;
    const int lane = tid & 63;
    const int q4   = lane >> 4;
    const int cl   = lane & 15;
    const int wr   = wave >> 1, wc = wave & 1;
    const int id   = blockIdx.y * gridDim.x + blockIdx.x;   // dispatch-linear
    const int cpx  = (gridDim.x * gridDim.y) >> 3;          // grid % 8 == 0
    const int swz  = (id & 7) * cpx + (id >> 3);
    const int m0   = (swz / NY) * 128;
    const int n0   = (swz % NY) * 128;
    const int srow = lane >> 2;          // 0..15
    const int skoff = (lane & 3) * 8;    // elements

    const f32x4 zero = {0.f, 0.f, 0.f, 0.f};
    f32x4 acc[4][4];
#pragma unroll
    for (int i = 0; i < 4; ++i)
#pragma unroll
        for (int j = 0; j < 4; ++j) acc[i][j] = zero;

    for (int k0 = 0; k0 < K; k0 += 32) {
        __syncthreads();
#pragma unroll
        for (int cc = 0; cc < 2; ++cc) {
            int r = 32 * wave + 16 * cc + srow;
            const u16* ga;
            if (AHB) {
                int hh = k0 >> 6;
                ga = A + ((size_t)hh * M + (m0 + r)) * 64 + (k0 & 63) + skoff;
            } else {
                ga = A + (size_t)(m0 + r) * K + k0 + skoff;
            }
            __builtin_amdgcn_global_load_lds(
                (const __attribute__((address_space(1))) void*)ga,
                (__attribute__((address_space(3))) void*)(&As[32 * wave + 16 * cc][0]),
                16, 0, 0);
            const u16* gb = Bt + (size_t)(n0 + r) * K + k0 + skoff;
            __builtin_amdgcn_global_load_lds(
                (const __attribute__((address_space(1))) void*)gb,
                (__attribute__((address_space(3))) void*)(&Bs[32 * wave + 16 * cc][0]),
                16, 0, 0);
        }
        __syncthreads();
        bf16x8 af[4], bfr[4];
#pragma unroll
        for (int i = 0; i < 4; ++i)
            af[i] = *(const bf16x8*)&As[64 * wr + 16 * i + cl][q4 * 8];
#pragma unroll
        for (int j = 0; j < 4; ++j)
            bfr[j] = *(const bf16x8*)&Bs[64 * wc + 16 * j + cl][q4 * 8];
#pragma unroll
        for (int i = 0; i < 4; ++i)
#pragma unroll
            for (int j = 0; j < 4; ++j)
                acc[i][j] = __builtin_amdgcn_mfma_f32_16x16x32_bf16(
                    af[i], bfr[j], acc[i][j], 0, 0, 0);
    }

#pragma unroll
    for (int i = 0; i < 4; ++i)
#pragma unroll
        for (int j = 0; j < 4; ++j)
#pragma unroll
            for (int r = 0; r < 4; ++r) {
                int row = m0 + 64 * wr + 16 * i + q4 * 4 + r;
                int col = n0 + 64 * wc + 16 * j + cl;
                if (BF16OUT)
                    ((u16*)Cout)[(size_t)row * N + col] = f2bf(acc[i][j][r]);
                else
                    ((float*)Cout)[(size_t)row * N + col] = acc[i][j][r];
            }
}

// ---------------- fused attention, 1 block per (bt, h) ----------------
// R5b restructure (in-register P, no cross-lane ops in the hot loop):
//  - pre-pass: thread t computes rms(K row t), rms(Q row t) in-thread into
//    rk_s/rq_s LDS, alongside V^T staging.
//  - swapped QK^T: s = mfma(K, Q) -> C[k][q]; q = cl is lane-local.
//  - P stays in registers ENTIRELY IN-LANE: the QK output's per-lane k-set
//    {4q4+r} u {16+4q4+r} is already a bijection over (q4,e), so the PV
//    A-fragment is just the packed bf16 words, with V read in the same
//    k-order kappa(q4,e) = 4q4+e (e<4), 16+4q4+(e-4) (e>=4).
//    (No permlane/shuffle/LDS needed for P at all.)
//  - l = sum(P) as in-lane scalars; cross-q4 reduce once at the end.
// Removed vs R4: P LDS buffer (20 KB), per-tile shfl_xor+rsqrt chain, rqc
// redistribution, mfma-with-ones (-16 accum regs, -32 MFMAs).
// Kept (verified): XCD-grouped head remap, dense head-blocked AO.
__global__ __launch_bounds__(256, 3) void attention_kernel(
    const u16* __restrict__ qkv, const float* __restrict__ qw,
    const float* __restrict__ kw, u16* __restrict__ ao)
{
    // bijective XCD-chunk remap: blocks sharing (bt,kvh) land on one XCD.
    const int lg  = (blockIdx.x & 7) * 256 + (blockIdx.x >> 3);
    const int bt  = lg >> 4;
    const int h   = lg & 15;
    const int kvh = h >> 2;          // GROUPS=4
    const int tid  = threadIdx.x;
    const int wave = tid >> 6;
    const int lane = tid & 63;
    const int q4   = lane >> 4;
    const int cl   = lane & 15;

    __shared__ __align__(16) u16 Vt[64][264];   // V^T, 528B rows (16B aligned)
    __shared__ float rk_s[256];                 // rsqrt(ms(K row))*C1
    __shared__ float rq_s[256];                 // rsqrt(ms(Q row))

    // ---- pre-pass: thread t owns source row t ----
    {
        const u16* rowb = qkv + (size_t)(bt * 256 + tid) * NQKV;
        const u16* vrow = rowb + 1280 + kvh * 64;
#pragma unroll
        for (int ch = 0; ch < 8; ++ch) {
            u16x8 v8 = *(const u16x8*)(vrow + ch * 8);
#pragma unroll
            for (int e = 0; e < 8; ++e) Vt[ch * 8 + e][tid] = v8[e];
        }
        float ssk = 0.f, ssq = 0.f;
#pragma unroll
        for (int ch = 0; ch < 8; ++ch) {
            uint4 kk = *(const uint4*)(rowb + 1024 + kvh * 64 + ch * 8);
            uint4 qq = *(const uint4*)(rowb + h * 64 + ch * 8);
            const u32* uk = (const u32*)&kk;
            const u32* uq = (const u32*)&qq;
#pragma unroll
            for (int e = 0; e < 4; ++e) {
                float lo = bf_lo(uk[e]), hi = bf_hi(uk[e]);
                ssk += lo * lo + hi * hi;
                lo = bf_lo(uq[e]); hi = bf_hi(uq[e]);
                ssq += lo * lo + hi * hi;
            }
        }
        rk_s[tid] = rsqrtf(ssk * (1.0f / 64.0f) + 1e-6f) * C1_;
        rq_s[tid] = rsqrtf(ssq * (1.0f / 64.0f) + 1e-6f);
    }
    __syncthreads();

    const u16* qbase = qkv + (size_t)(bt * 256) * NQKV + h * 64;
    const u16* kbase = qkv + (size_t)(bt * 256) * NQKV + 1024 + kvh * 64;

    // ---- Q fragments: load + apply wq*wk (RNE repack; exact when w==1) ----
    float wqk[2][8];
#pragma unroll
    for (int ks = 0; ks < 2; ++ks)
#pragma unroll
        for (int e = 0; e < 8; ++e) {
            int d = ks * 32 + q4 * 8 + e;
            wqk[ks][e] = qw[d] * kw[d];
        }
    uint4 qa[2][4];          // [ks][i], each = bf16x8, Q row = wave*64+16i+cl
#pragma unroll
    for (int i = 0; i < 4; ++i)
#pragma unroll
        for (int ks = 0; ks < 2; ++ks) {
            qa[ks][i] = *(const uint4*)(qbase +
                (size_t)(wave * 64 + 16 * i + cl) * NQKV + ks * 32 + q4 * 8);
            u32* u = (u32*)&qa[ks][i];
#pragma unroll
            for (int e = 0; e < 4; ++e) {
                float lo = bf_lo(u[e]) * wqk[ks][2 * e];
                float hi = bf_hi(u[e]) * wqk[ks][2 * e + 1];
                u[e] = pack_rne(lo, hi);
            }
        }
    float rq[4];
#pragma unroll
    for (int i = 0; i < 4; ++i)
        rq[i] = rq_s[wave * 64 + 16 * i + cl];

    const f32x4 zero = {0.f, 0.f, 0.f, 0.f};
    f32x4 o[4][4];
    float lsum[4] = {0.f, 0.f, 0.f, 0.f};
#pragma unroll
    for (int i = 0; i < 4; ++i)
#pragma unroll
        for (int j = 0; j < 4; ++j) o[i][j] = zero;

    for (int nb = 0; nb < 4; ++nb) {
#pragma unroll
        for (int jh = 0; jh < 2; ++jh) {       // 32-k chunk
            const int cb = nb * 64 + jh * 32;
            // per-chunk rk scalars (LDS broadcast reads, no shuffles)
            float rkc[2][4];
#pragma unroll
            for (int jj = 0; jj < 2; ++jj)
#pragma unroll
                for (int r = 0; r < 4; ++r)
                    rkc[jj][r] = rk_s[cb + 16 * jj + 4 * q4 + r];
            // K fragments for both 16-k tiles (L2-warm after pre-pass)
            uint4 kb[2][2];
#pragma unroll
            for (int jj = 0; jj < 2; ++jj)
#pragma unroll
                for (int ks = 0; ks < 2; ++ks)
                    kb[jj][ks] = *(const uint4*)(kbase +
                        (size_t)(cb + 16 * jj + cl) * NQKV + ks * 32 + q4 * 8);
            // V B-fragments in the in-lane kappa k-order:
            //   e=0..3 -> k = cb + 4q4 + e ; e=4..7 -> k = cb + 16 + 4q4 + (e-4)
            bf16x8 vb[4];
#pragma unroll
            for (int j2 = 0; j2 < 4; ++j2) {
                uint2 lo4 = *(const uint2*)&Vt[16 * j2 + cl][cb + 4 * q4];
                uint2 hi4 = *(const uint2*)&Vt[16 * j2 + cl][cb + 16 + 4 * q4];
                u32x4v vv = {lo4.x, lo4.y, hi4.x, hi4.y};
                vb[j2] = *(const bf16x8*)&vv;
            }
#pragma unroll
            for (int i = 0; i < 4; ++i) {
                // swapped QK^T: C[k-row=4q4+r][q=cl]
                f32x4 s0 = __builtin_amdgcn_mfma_f32_16x16x32_bf16(
                    *(const bf16x8*)&kb[0][0], *(const bf16x8*)&qa[0][i], zero, 0, 0, 0);
                s0 = __builtin_amdgcn_mfma_f32_16x16x32_bf16(
                    *(const bf16x8*)&kb[0][1], *(const bf16x8*)&qa[1][i], s0, 0, 0, 0);
                f32x4 s1 = __builtin_amdgcn_mfma_f32_16x16x32_bf16(
                    *(const bf16x8*)&kb[1][0], *(const bf16x8*)&qa[0][i], zero, 0, 0, 0);
                s1 = __builtin_amdgcn_mfma_f32_16x16x32_bf16(
                    *(const bf16x8*)&kb[1][1], *(const bf16x8*)&qa[1][i], s1, 0, 0, 0);
                float p0[4], p1[4];
#pragma unroll
                for (int r = 0; r < 4; ++r) {
                    float e2a = __builtin_amdgcn_exp2f(s0[r] * rq[i] * rkc[0][r]);
                    float rca = __builtin_amdgcn_rcpf(e2a + 1.0f);
                    p0[r] = __builtin_amdgcn_exp2f(fmaf(-A2_, rca, B2_));
                    float e2b = __builtin_amdgcn_exp2f(s1[r] * rq[i] * rkc[1][r]);
                    float rcb = __builtin_amdgcn_rcpf(e2b + 1.0f);
                    p1[r] = __builtin_amdgcn_exp2f(fmaf(-A2_, rcb, B2_));
                    lsum[i] += p0[r] + p1[r];
                }
                // P -> bf16 in-register; per-lane k-set is already bijective
                // over (q4,e), so the A-fragment is just the packed words.
                u32x4v paw = {pack_rne(p0[0], p0[1]), pack_rne(p0[2], p0[3]),
                              pack_rne(p1[0], p1[1]), pack_rne(p1[2], p1[3])};
                bf16x8 pa = *(const bf16x8*)&paw;
#pragma unroll
                for (int j2 = 0; j2 < 4; ++j2)
                    o[i][j2] = __builtin_amdgcn_mfma_f32_16x16x32_bf16(
                        pa, vb[j2], o[i][j2], 0, 0, 0);
            }
        }
    }

    // ---- finish l across q4 groups, normalize, dense head-blocked store ----
#pragma unroll
    for (int i = 0; i < 4; ++i) {
        lsum[i] += __shfl_xor(lsum[i], 16, 64);
        lsum[i] += __shfl_xor(lsum[i], 32, 64);
    }
    u16* aob = ao + ((size_t)h * ROWS + (size_t)(bt * 256 + wave * 64)) * 64;
#pragma unroll
    for (int i = 0; i < 4; ++i)
#pragma unroll
        for (int r = 0; r < 4; ++r) {
            float inv = 1.0f / __shfl(lsum[i], 4 * q4 + r, 64);
            int lr = 16 * i + 4 * q4 + r;     // row within wave's 64
#pragma unroll
            for (int j = 0; j < 4; ++j)
                aob[(size_t)lr * 64 + 16 * j + cl] = f2bf(o[i][j][r] * inv);
        }
}

// ---------------- host launch ----------------
extern "C" void kernel_launch(void* const* d_in, const int* in_sizes, int n_in,
                              void* d_out, int out_size, void* d_ws, size_t ws_size,
                              hipStream_t stream)
{
    const float* x  = (const float*)d_in[0];
    const float* Wq = (const float*)d_in[1];
    const float* Wk = (const float*)d_in[2];
    const float* Wv = (const float*)d_in[3];
    const float* Wo = (const float*)d_in[4];
    const float* qw = (const float*)d_in[5];
    const float* kw = (const float*)d_in[6];
    float* out = (float*)d_out;

    char* ws = (char*)d_ws;
    u16* Xb  = (u16*)(ws);                            // 32768x1024 bf16 (64 MB)
    u16* QKV = (u16*)(ws + (size_t)67108864);         // 32768x1536 bf16 (96 MB)
    u16* AO  = (u16*)(ws + (size_t)167772160);        // head-blocked [16][32768][64] bf16 (64 MB)
    u16* WcT = (u16*)(ws + (size_t)234881024);        // 1536x1024 bf16  (3 MB)
    u16* WoT = (u16*)(ws + (size_t)238026752);        // 1024x1024 bf16  (2 MB)

    // x -> bf16
    f32_to_bf16_vec<<<dim3(32768), dim3(256), 0, stream>>>(x, Xb, 8388608);
    // W^T (concatenated q|k|v) and Wo^T, bf16
    transpose_bf16<<<dim3(32, 32), dim3(256), 0, stream>>>(Wq, WcT, 1024, 1024);
    transpose_bf16<<<dim3(8, 32), dim3(256), 0, stream>>>(Wk, WcT + (size_t)1024 * 1024, 1024, 256);
    transpose_bf16<<<dim3(8, 32), dim3(256), 0, stream>>>(Wv, WcT + (size_t)1280 * 1024, 1024, 256);
    transpose_bf16<<<dim3(32, 32), dim3(256), 0, stream>>>(Wo, WoT, 1024, 1024);
    // QKV projection (q,k unnormalized; attention fuses rmsnorm)
    gemm_bt<true, 12, false><<<dim3(256, 12), dim3(256), 0, stream>>>(Xb, WcT, (void*)QKV, ROWS, NQKV, 1024);
    // attention -> head-blocked AO
    attention_kernel<<<dim3(2048), dim3(256), 0, stream>>>(QKV, qw, kw, AO);
    // output projection (A head-blocked) -> fp32 d_out
    gemm_bt<false, 8, true><<<dim3(256, 8), dim3(256), 0, stream>>>(AO, WoT, (void*)out, ROWS, DMODEL, 1024);
}

// Round 7
// 576.403 us; speedup vs baseline: 1.2310x; 1.2310x over previous
//
#include <hip/hip_runtime.h>
#include <cstdint>
#include <cstddef>

typedef __bf16 bf16x8 __attribute__((ext_vector_type(8)));
typedef float f32x4 __attribute__((ext_vector_type(4)));
typedef unsigned short u16;
typedef unsigned int u32;
typedef unsigned short u16x8 __attribute__((ext_vector_type(8)));
typedef unsigned int u32x4v __attribute__((ext_vector_type(4)));

#define ROWS 32768       // B*T*S
#define DMODEL 1024
#define NQKV 1536        // H*HD + 2*KVH*HD
// folded softcap constants: logits z = dot*rq*rk*0.125, capped = 50*tanh(z/50)
//   e2 = exp2(dot*rq*rk * C1),  C1 = 2*0.125/50*log2(e)
//   p  = exp2(B2 - A2 * rcp(e2+1)),  A2 = 100*log2(e), B2 = 50*log2(e)
#define C1_ 0.0072134752044448170f
#define A2_ 144.26950408889634f
#define B2_ 72.13475204444817f

__device__ __forceinline__ u16 f2bf(float f) {
    unsigned u = __float_as_uint(f);
    u += 0x7fffu + ((u >> 16) & 1u);   // RNE
    return (u16)(u >> 16);
}
__device__ __forceinline__ float bf_lo(u32 u) { return __uint_as_float(u << 16); }
__device__ __forceinline__ float bf_hi(u32 u) { return __uint_as_float(u & 0xffff0000u); }
__device__ __forceinline__ u32 pack_rne(float lo, float hi) {
    return (u32)f2bf(lo) | ((u32)f2bf(hi) << 16);
}

// ---------------- elementwise f32 -> bf16 (x) ----------------
__global__ __launch_bounds__(256) void f32_to_bf16_vec(
    const float* __restrict__ in, u16* __restrict__ out, int n4)
{
    int i = blockIdx.x * 256 + threadIdx.x;
    if (i >= n4) return;
    float4 f = ((const float4*)in)[i];
    ushort4 u;
    u.x = f2bf(f.x); u.y = f2bf(f.y); u.z = f2bf(f.z); u.w = f2bf(f.w);
    ((ushort4*)out)[i] = u;
}

// ---------------- transpose f32 [R][C] -> bf16 [C][R] ----------------
__global__ __launch_bounds__(256) void transpose_bf16(
    const float* __restrict__ src, u16* __restrict__ dst, int R, int C)
{
    __shared__ float tile[32][33];
    int c0 = blockIdx.x * 32;
    int r0 = blockIdx.y * 32;
    int tx = threadIdx.x & 31;
    int ty = threadIdx.x >> 5;        // 0..7
#pragma unroll
    for (int i = 0; i < 32; i += 8)
        tile[ty + i][tx] = src[(size_t)(r0 + ty + i) * C + (c0 + tx)];
    __syncthreads();
#pragma unroll
    for (int i = 0; i < 32; i += 8)
        dst[(size_t)(c0 + ty + i) * R + (r0 + tx)] = f2bf(tile[tx][ty + i]);
}

// ---------------- MFMA GEMM: A[M][K] bf16 @ Bt[N][K] bf16 -> C[M][N] ----------------
// XCD-chunked swizzle, n-tile fastest inside a chunk. AHB: A is head-blocked
// [16][M][64] (attention output layout).
template<bool BF16OUT, int NY, bool AHB>
__global__ __launch_bounds__(256) void gemm_bt(
    const u16* __restrict__ A, const u16* __restrict__ Bt,
    void* __restrict__ Cout, int M, int N, int K)
{
    __shared__ u16 As[128][32];
    __shared__ u16 Bs[128][32];
    const int tid  = threadIdx.x;
    const int wave = tid >> 6;
    const int lane = tid & 63;
    const int q4   = lane >> 4;
    const int cl   = lane & 15;
    const int wr   = wave >> 1, wc = wave & 1;
    const int id   = blockIdx.y * gridDim.x + blockIdx.x;   // dispatch-linear
    const int cpx  = (gridDim.x * gridDim.y) >> 3;          // grid % 8 == 0
    const int swz  = (id & 7) * cpx + (id >> 3);
    const int m0   = (swz / NY) * 128;
    const int n0   = (swz % NY) * 128;
    const int srow = lane >> 2;          // 0..15
    const int skoff = (lane & 3) * 8;    // elements

    const f32x4 zero = {0.f, 0.f, 0.f, 0.f};
    f32x4 acc[4][4];
#pragma unroll
    for (int i = 0; i < 4; ++i)
#pragma unroll
        for (int j = 0; j < 4; ++j) acc[i][j] = zero;

    for (int k0 = 0; k0 < K; k0 += 32) {
        __syncthreads();
#pragma unroll
        for (int cc = 0; cc < 2; ++cc) {
            int r = 32 * wave + 16 * cc + srow;
            const u16* ga;
            if (AHB) {
                int hh = k0 >> 6;
                ga = A + ((size_t)hh * M + (m0 + r)) * 64 + (k0 & 63) + skoff;
            } else {
                ga = A + (size_t)(m0 + r) * K + k0 + skoff;
            }
            __builtin_amdgcn_global_load_lds(
                (const __attribute__((address_space(1))) void*)ga,
                (__attribute__((address_space(3))) void*)(&As[32 * wave + 16 * cc][0]),
                16, 0, 0);
            const u16* gb = Bt + (size_t)(n0 + r) * K + k0 + skoff;
            __builtin_amdgcn_global_load_lds(
                (const __attribute__((address_space(1))) void*)gb,
                (__attribute__((address_space(3))) void*)(&Bs[32 * wave + 16 * cc][0]),
                16, 0, 0);
        }
        __syncthreads();
        bf16x8 af[4], bfr[4];
#pragma unroll
        for (int i = 0; i < 4; ++i)
            af[i] = *(const bf16x8*)&As[64 * wr + 16 * i + cl][q4 * 8];
#pragma unroll
        for (int j = 0; j < 4; ++j)
            bfr[j] = *(const bf16x8*)&Bs[64 * wc + 16 * j + cl][q4 * 8];
#pragma unroll
        for (int i = 0; i < 4; ++i)
#pragma unroll
            for (int j = 0; j < 4; ++j)
                acc[i][j] = __builtin_amdgcn_mfma_f32_16x16x32_bf16(
                    af[i], bfr[j], acc[i][j], 0, 0, 0);
    }

#pragma unroll
    for (int i = 0; i < 4; ++i)
#pragma unroll
        for (int j = 0; j < 4; ++j)
#pragma unroll
            for (int r = 0; r < 4; ++r) {
                int row = m0 + 64 * wr + 16 * i + q4 * 4 + r;
                int col = n0 + 64 * wc + 16 * j + cl;
                if (BF16OUT)
                    ((u16*)Cout)[(size_t)row * N + col] = f2bf(acc[i][j][r]);
                else
                    ((float*)Cout)[(size_t)row * N + col] = acc[i][j][r];
            }
}

// ---------------- fused attention, 1 block per (bt, h) ----------------
// R7: 8 waves x 32 Q-rows (512 threads). Same in-register-P dataflow as R6
// (swapped QK^T, in-lane kappa k-order, l as scalars) but per-wave register
// demand ~116 (o 32 + qa 16 + pw 8 + vb 16 + kb 8 jj-scoped + scalars) --
// fits 128-reg / 4-waves-per-SIMD budget with zero spill (R6's ~182 demand
// at the 170 cap caused ~240 MB/dispatch of symmetric spill R+W traffic).
// launch_bounds(512,4) targets 16 waves/CU (~50% occupancy vs 21-28%).
// Kept (verified): XCD-grouped head remap, dense head-blocked AO output.
__global__ __launch_bounds__(512, 4) void attention_kernel(
    const u16* __restrict__ qkv, const float* __restrict__ qw,
    const float* __restrict__ kw, u16* __restrict__ ao)
{
    // bijective XCD-chunk remap: blocks sharing (bt,kvh) land on one XCD.
    const int lg  = (blockIdx.x & 7) * 256 + (blockIdx.x >> 3);
    const int bt  = lg >> 4;
    const int h   = lg & 15;
    const int kvh = h >> 2;          // GROUPS=4
    const int tid  = threadIdx.x;
    const int wave = tid >> 6;       // 0..7
    const int lane = tid & 63;
    const int q4   = lane >> 4;
    const int cl   = lane & 15;

    __shared__ __align__(16) u16 Vt[64][264];   // V^T, 528B rows (16B aligned)
    __shared__ float rk_s[256];                 // rsqrt(ms(K row))*C1
    __shared__ float rq_s[256];                 // rsqrt(ms(Q row))

    // ---- pre-pass (512 threads): half a V-row per thread; waves 0-3 do
    //      K-row rms, waves 4-7 do Q-row rms (wave-uniform split) ----
    {
        const int s  = tid >> 1;         // 0..255
        const int hb = tid & 1;          // which half of the 64 dims
        const u16* vrow = qkv + (size_t)(bt * 256 + s) * NQKV + 1280 + kvh * 64 + hb * 32;
#pragma unroll
        for (int ch = 0; ch < 4; ++ch) {
            u16x8 v8 = *(const u16x8*)(vrow + ch * 8);
#pragma unroll
            for (int e = 0; e < 8; ++e) Vt[hb * 32 + ch * 8 + e][s] = v8[e];
        }
        const int t = tid & 255;
        const u16* rowb = qkv + (size_t)(bt * 256 + t) * NQKV;
        const u16* src  = (tid < 256) ? (rowb + 1024 + kvh * 64) : (rowb + h * 64);
        float ss = 0.f;
#pragma unroll
        for (int ch = 0; ch < 8; ++ch) {
            uint4 kk = *(const uint4*)(src + ch * 8);
            const u32* uk = (const u32*)&kk;
#pragma unroll
            for (int e = 0; e < 4; ++e) {
                float lo = bf_lo(uk[e]), hi = bf_hi(uk[e]);
                ss += lo * lo + hi * hi;
            }
        }
        float rv = rsqrtf(ss * (1.0f / 64.0f) + 1e-6f);
        if (tid < 256) rk_s[t] = rv * C1_;
        else           rq_s[t] = rv;
    }
    __syncthreads();

    const u16* qbase = qkv + (size_t)(bt * 256) * NQKV + h * 64;
    const u16* kbase = qkv + (size_t)(bt * 256) * NQKV + 1024 + kvh * 64;

    // ---- Q fragments (2 tiles of 16 rows): load + apply wq*wk ----
    float wqk[2][8];
#pragma unroll
    for (int ks = 0; ks < 2; ++ks)
#pragma unroll
        for (int e = 0; e < 8; ++e) {
            int d = ks * 32 + q4 * 8 + e;
            wqk[ks][e] = qw[d] * kw[d];
        }
    uint4 qa[2][2];          // [ks][i], Q row = wave*32 + 16i + cl
#pragma unroll
    for (int i = 0; i < 2; ++i)
#pragma unroll
        for (int ks = 0; ks < 2; ++ks) {
            qa[ks][i] = *(const uint4*)(qbase +
                (size_t)(wave * 32 + 16 * i + cl) * NQKV + ks * 32 + q4 * 8);
            u32* u = (u32*)&qa[ks][i];
#pragma unroll
            for (int e = 0; e < 4; ++e) {
                float lo = bf_lo(u[e]) * wqk[ks][2 * e];
                float hi = bf_hi(u[e]) * wqk[ks][2 * e + 1];
                u[e] = pack_rne(lo, hi);
            }
        }
    float rq[2];
#pragma unroll
    for (int i = 0; i < 2; ++i)
        rq[i] = rq_s[wave * 32 + 16 * i + cl];

    const f32x4 zero = {0.f, 0.f, 0.f, 0.f};
    f32x4 o[2][4];
    float lsum[2] = {0.f, 0.f};
#pragma unroll
    for (int i = 0; i < 2; ++i)
#pragma unroll
        for (int j = 0; j < 4; ++j) o[i][j] = zero;

    for (int nb = 0; nb < 4; ++nb) {
#pragma unroll
        for (int jh = 0; jh < 2; ++jh) {       // 32-k chunk
            const int cb = nb * 64 + jh * 32;
            // per-chunk rk scalars (LDS broadcast reads)
            float rkc[2][4];
#pragma unroll
            for (int jj = 0; jj < 2; ++jj)
#pragma unroll
                for (int r = 0; r < 4; ++r)
                    rkc[jj][r] = rk_s[cb + 16 * jj + 4 * q4 + r];
            // QK^T + softcap, jj-scoped K fragments (short live range)
            u32 pw[2][4];    // packed P words per i-tile, kappa order
#pragma unroll
            for (int jj = 0; jj < 2; ++jj) {
                uint4 kb0 = *(const uint4*)(kbase +
                    (size_t)(cb + 16 * jj + cl) * NQKV + q4 * 8);
                uint4 kb1 = *(const uint4*)(kbase +
                    (size_t)(cb + 16 * jj + cl) * NQKV + 32 + q4 * 8);
#pragma unroll
                for (int i = 0; i < 2; ++i) {
                    f32x4 s = __builtin_amdgcn_mfma_f32_16x16x32_bf16(
                        *(const bf16x8*)&kb0, *(const bf16x8*)&qa[0][i], zero, 0, 0, 0);
                    s = __builtin_amdgcn_mfma_f32_16x16x32_bf16(
                        *(const bf16x8*)&kb1, *(const bf16x8*)&qa[1][i], s, 0, 0, 0);
                    float p[4];
#pragma unroll
                    for (int r = 0; r < 4; ++r) {
                        float e2 = __builtin_amdgcn_exp2f(s[r] * rq[i] * rkc[jj][r]);
                        float rc = __builtin_amdgcn_rcpf(e2 + 1.0f);
                        p[r] = __builtin_amdgcn_exp2f(fmaf(-A2_, rc, B2_));
                    }
                    lsum[i] += (p[0] + p[1]) + (p[2] + p[3]);
                    pw[i][2 * jj]     = pack_rne(p[0], p[1]);
                    pw[i][2 * jj + 1] = pack_rne(p[2], p[3]);
                }
            }
            // V B-fragments in the in-lane kappa k-order:
            //   e=0..3 -> k = cb + 4q4 + e ; e=4..7 -> k = cb + 16 + 4q4 + (e-4)
            bf16x8 vb[4];
#pragma unroll
            for (int j2 = 0; j2 < 4; ++j2) {
                uint2 lo4 = *(const uint2*)&Vt[16 * j2 + cl][cb + 4 * q4];
                uint2 hi4 = *(const uint2*)&Vt[16 * j2 + cl][cb + 16 + 4 * q4];
                u32x4v vv = {lo4.x, lo4.y, hi4.x, hi4.y};
                vb[j2] = *(const bf16x8*)&vv;
            }
#pragma unroll
            for (int i = 0; i < 2; ++i) {
                u32x4v paw = {pw[i][0], pw[i][1], pw[i][2], pw[i][3]};
                bf16x8 pa = *(const bf16x8*)&paw;
#pragma unroll
                for (int j2 = 0; j2 < 4; ++j2)
                    o[i][j2] = __builtin_amdgcn_mfma_f32_16x16x32_bf16(
                        pa, vb[j2], o[i][j2], 0, 0, 0);
            }
        }
    }

    // ---- finish l across q4 groups, normalize, dense head-blocked store ----
#pragma unroll
    for (int i = 0; i < 2; ++i) {
        lsum[i] += __shfl_xor(lsum[i], 16, 64);
        lsum[i] += __shfl_xor(lsum[i], 32, 64);
    }
    u16* aob = ao + ((size_t)h * ROWS + (size_t)(bt * 256 + wave * 32)) * 64;
#pragma unroll
    for (int i = 0; i < 2; ++i)
#pragma unroll
        for (int r = 0; r < 4; ++r) {
            float inv = 1.0f / __shfl(lsum[i], 4 * q4 + r, 64);
            int lr = 16 * i + 4 * q4 + r;     // row within wave's 32
#pragma unroll
            for (int j = 0; j < 4; ++j)
                aob[(size_t)lr * 64 + 16 * j + cl] = f2bf(o[i][j][r] * inv);
        }
}

// ---------------- host launch ----------------
extern "C" void kernel_launch(void* const* d_in, const int* in_sizes, int n_in,
                              void* d_out, int out_size, void* d_ws, size_t ws_size,
                              hipStream_t stream)
{
    const float* x  = (const float*)d_in[0];
    const float* Wq = (const float*)d_in[1];
    const float* Wk = (const float*)d_in[2];
    const float* Wv = (const float*)d_in[3];
    const float* Wo = (const float*)d_in[4];
    const float* qw = (const float*)d_in[5];
    const float* kw = (const float*)d_in[6];
    float* out = (float*)d_out;

    char* ws = (char*)d_ws;
    u16* Xb  = (u16*)(ws);                            // 32768x1024 bf16 (64 MB)
    u16* QKV = (u16*)(ws + (size_t)67108864);         // 32768x1536 bf16 (96 MB)
    u16* AO  = (u16*)(ws + (size_t)167772160);        // head-blocked [16][32768][64] bf16 (64 MB)
    u16* WcT = (u16*)(ws + (size_t)234881024);        // 1536x1024 bf16  (3 MB)
    u16* WoT = (u16*)(ws + (size_t)238026752);        // 1024x1024 bf16  (2 MB)

    // x -> bf16
    f32_to_bf16_vec<<<dim3(32768), dim3(256), 0, stream>>>(x, Xb, 8388608);
    // W^T (concatenated q|k|v) and Wo^T, bf16
    transpose_bf16<<<dim3(32, 32), dim3(256), 0, stream>>>(Wq, WcT, 1024, 1024);
    transpose_bf16<<<dim3(8, 32), dim3(256), 0, stream>>>(Wk, WcT + (size_t)1024 * 1024, 1024, 256);
    transpose_bf16<<<dim3(8, 32), dim3(256), 0, stream>>>(Wv, WcT + (size_t)1280 * 1024, 1024, 256);
    transpose_bf16<<<dim3(32, 32), dim3(256), 0, stream>>>(Wo, WoT, 1024, 1024);
    // QKV projection (q,k unnormalized; attention fuses rmsnorm)
    gemm_bt<true, 12, false><<<dim3(256, 12), dim3(256), 0, stream>>>(Xb, WcT, (void*)QKV, ROWS, NQKV, 1024);
    // attention -> head-blocked AO (8 waves x 32 Q-rows)
    attention_kernel<<<dim3(2048), dim3(512), 0, stream>>>(QKV, qw, kw, AO);
    // output projection (A head-blocked) -> fp32 d_out
    gemm_bt<false, 8, true><<<dim3(256, 8), dim3(256), 0, stream>>>(AO, WoT, (void*)out, ROWS, DMODEL, 1024);
}